// Round 20
// baseline (173.816 us; speedup 1.0000x reference)
//
#include <hip/hip_runtime.h>
#include <hip/hip_bf16.h>

#define NB 65536

typedef __attribute__((ext_vector_type(8))) short short8;
typedef __attribute__((ext_vector_type(4))) short short4v;
typedef __attribute__((ext_vector_type(4))) float f32x4;
typedef __attribute__((ext_vector_type(16))) float f32x16;
typedef __attribute__((ext_vector_type(4))) unsigned int u32x4;

__device__ inline short f2bf(float f) {
    unsigned u = __builtin_bit_cast(unsigned, f);
    unsigned r = (u + 0x7fffu + ((u >> 16) & 1u)) >> 16;   // RNE
    return (short)(unsigned short)r;
}
__device__ inline float b2f(short s) {
    return __builtin_bit_cast(float, (unsigned)((unsigned short)s) << 16);
}
__device__ inline unsigned pkbf(float lo, float hi) {
    return ((unsigned)(unsigned short)f2bf(hi) << 16) | (unsigned)(unsigned short)f2bf(lo);
}

#define MLPW_CNT 109568
#define WEFF_CNT 51200
// prep index-space extents
#define A0 (MLPW_CNT + WEFF_CNT + 320)   // aw0T start
#define A1 (A0 + 2048)                   // aw1T start
#define A2 (A1 + 2048)                   // sTab start
#define A3 (A2 + 100)                    // biasP start (512 f32)
#define PREP_TOT (A3 + 512)

// ---------------------------------------------------------------------------
// Kernel 0: prep (unchanged, proven)
// ---------------------------------------------------------------------------
__global__ void __launch_bounds__(256) prep_kernel(
    const float* __restrict__ w0, const float* __restrict__ w1,
    const float* __restrict__ w2, const float* __restrict__ w3,
    const float* __restrict__ w4,
    const float* __restrict__ b0, const float* __restrict__ b1,
    const float* __restrict__ b2, const float* __restrict__ b3,
    const float* __restrict__ b4,
    const float* __restrict__ c1w, const float* __restrict__ c1b,
    const float* __restrict__ c2w, const float* __restrict__ c2b,
    const float* __restrict__ aw0, const float* __restrict__ aw1,
    short* __restrict__ wt, short* __restrict__ weff, float* __restrict__ beff,
    short* __restrict__ aw0T, short* __restrict__ aw1T, float* __restrict__ sTab,
    float* __restrict__ biasP)
{
    int idx = blockIdx.x * 256 + threadIdx.x;
    if (idx < MLPW_CNT) {
        const float* W; int N, KT, base;
        if (idx < 65536)       { W = w0; N = 256; KT = 16; base = 0; }
        else if (idx < 98304)  { W = w1; N = 128; KT = 16; base = 65536; }
        else if (idx < 106496) { W = w2; N = 64;  KT = 8;  base = 98304; }
        else if (idx < 108544) { W = w3; N = 32;  KT = 4;  base = 106496; }
        else                   { W = w4; N = 32;  KT = 2;  base = 108544; }
        int i  = idx - base;
        int nt = i / (KT * 512);
        int r1 = i - nt * (KT * 512);
        int kt = r1 >> 9;
        int l  = (r1 & 511) >> 3;
        int j  = i & 7;
        int n  = nt * 32 + (l & 31);
        int k  = kt * 16 + ((l >> 5) << 3) + j;
        wt[idx] = f2bf(W[k * N + n]);
    } else if (idx < MLPW_CNT + WEFF_CNT) {
        int it = idx - MLPW_CNT;
        int n = it / 160, k = it - n * 160;
        float acc = 0.f;
        if (n < 300 && k < 147) {
            int oc = n % 12, p = n / 12, oy = p / 5, ox = p - oy * 5;
            int ci = k % 3,  t = k / 3, iy = t / 7, ix = t - iy * 7;
            for (int y = 0; y < 5; ++y) {
                int ky = iy - y + 1, ly = y - oy + 1;
                if ((unsigned)ky < 5u && (unsigned)ly < 3u) {
                    for (int x = 0; x < 5; ++x) {
                        int kx = ix - x + 1, lx = x - ox + 1;
                        if ((unsigned)kx < 5u && (unsigned)lx < 3u) {
                            const float* p1 = c1w + ((ky * 5 + kx) * 3 + ci) * 8;
                            const float* p2 = c2w + ((ly * 3 + lx) * 8) * 12 + oc;
#pragma unroll
                            for (int c = 0; c < 8; ++c) acc += p1[c] * p2[c * 12];
                        }
                    }
                }
            }
        }
        weff[it] = f2bf(acc);
    } else if (idx < A0) {
        int n = idx - MLPW_CNT - WEFF_CNT;
        float acc = 0.f;
        if (n < 300) {
            int oc = n % 12, p = n / 12, oy = p / 5, ox = p - oy * 5;
            acc = c2b[oc];
            for (int y = 0; y < 5; ++y) {
                int ly = y - oy + 1;
                if ((unsigned)ly < 3u) {
                    for (int x = 0; x < 5; ++x) {
                        int lx = x - ox + 1;
                        if ((unsigned)lx < 3u) {
#pragma unroll
                            for (int c = 0; c < 8; ++c)
                                acc += c2w[((ly * 3 + lx) * 8 + c) * 12 + oc] * c1b[c];
                        }
                    }
                }
            }
        }
        beff[n] = acc;
    } else if (idx < A1) {
        int t = idx - A0;
        int n = t >> 6, k = t & 63;           // [32][64]
        aw0T[t] = (k < 48) ? f2bf(aw0[k * 32 + n]) : (short)0;
    } else if (idx < A2) {
        int t = idx - A1;
        int n = t >> 5, k = t & 31;           // [64][32]
        aw1T[t] = f2bf(aw1[k * 64 + n]);
    } else if (idx < A3) {
        int i = idx - A2;
        int p = i >> 2, s = i & 3;
        int h = p / 5, w = p - 5 * h;
        int u = (s >> 1) + 1, v = (s & 1) + 1;
        const float PI5 = 0.6283185307179586f;
        sTab[i] = cosf(((float)(h + 1) * PI5) * (float)u) *
                  cosf(((float)(w + 1) * PI5) * (float)v);
    } else if (idx < PREP_TOT) {
        int t = idx - A3;
        const float* B; int N, base;
        if (t < 256)      { B = b0; N = 256; base = 0; }
        else if (t < 384) { B = b1; N = 128; base = 256; }
        else if (t < 448) { B = b2; N = 64;  base = 384; }
        else if (t < 480) { B = b3; N = 32;  base = 448; }
        else              { B = b4; N = 32;  base = 480; }
        int u  = t - base;
        int h  = u / (N / 2);
        int w  = u - h * (N / 2);
        int nt = w >> 4, r = w & 15;
        biasP[t] = B[nt * 32 + (r & 3) + 8 * (r >> 2) + 4 * h];
    }
}

// ---------------------------------------------------------------------------
// Kernel 1 v5: register-resident MLP, LDS-staged weights, 8 waves/WG (R18).
// ---------------------------------------------------------------------------
template<int KT, int THREADS>
__device__ inline void stage_load(const short* __restrict__ src,
                                  short8* r, int tid)
{
    constexpr int CNT = (KT * 64 + THREADS - 1) / THREADS;
#pragma unroll
    for (int i = 0; i < CNT; ++i) {
        int idx = tid + i * THREADS;
        if (idx < KT * 64) r[i] = *(const short8*)(src + idx * 8);
    }
}
template<int KT, int THREADS>
__device__ inline void stage_write(short* __restrict__ dst,
                                   const short8* r, int tid)
{
    constexpr int CNT = (KT * 64 + THREADS - 1) / THREADS;
#pragma unroll
    for (int i = 0; i < CNT; ++i) {
        int idx = tid + i * THREADS;
        if (idx < KT * 64) *(short8*)(dst + idx * 8) = r[i];
    }
}

template<int K, int N, bool RELU, int THREADS>
__device__ inline void layerS(const short* __restrict__ wp,
                              const float* __restrict__ bp,
                              const u32x4* __restrict__ inF,
                              u32x4* __restrict__ outF,
                              short* __restrict__ sW0,
                              short* __restrict__ sW1,
                              int tid, int lane, int h)
{
    constexpr int KT = K / 16, NT = N / 32;
    constexpr int CNT = (KT * 64 + THREADS - 1) / THREADS;
    short8 tmp[CNT];

    stage_load<KT, THREADS>(wp, tmp, tid);
    stage_write<KT, THREADS>(sW0, tmp, tid);
    __syncthreads();

#pragma unroll
    for (int nt = 0; nt < NT; ++nt) {
        short* cur = (nt & 1) ? sW1 : sW0;
        short* nxt = (nt & 1) ? sW0 : sW1;
        if (nt + 1 < NT) stage_load<KT, THREADS>(wp + (nt + 1) * KT * 512, tmp, tid);

        f32x16 a;
#pragma unroll
        for (int r = 0; r < 16; ++r) a[r] = 0.f;
#pragma unroll
        for (int kt = 0; kt < KT; ++kt) {
            short8 wf = *(const short8*)(cur + kt * 512 + lane * 8);
            a = __builtin_amdgcn_mfma_f32_32x32x16_bf16(
                    wf, __builtin_bit_cast(short8, inF[kt]), a, 0, 0, 0);
        }
        const float* bpp = bp + h * (N / 2) + nt * 16;
        unsigned q[8];
#pragma unroll
        for (int i = 0; i < 8; ++i) {
            float v0 = a[2 * i] + bpp[2 * i];
            float v1 = a[2 * i + 1] + bpp[2 * i + 1];
            if (RELU) { v0 = fmaxf(v0, 0.f); v1 = fmaxf(v1, 0.f); }
            q[i] = pkbf(v0, v1);
        }
        unsigned xq[8];
#pragma unroll
        for (int i = 0; i < 8; ++i) xq[i] = (unsigned)__shfl_xor((int)q[i], 32, 64);
        u32x4 fa, fb;
        if (h == 0) {
            fa[0] = q[0];  fa[1] = q[1];  fa[2] = xq[0]; fa[3] = xq[1];
            fb[0] = q[4];  fb[1] = q[5];  fb[2] = xq[4]; fb[3] = xq[5];
        } else {
            fa[0] = xq[2]; fa[1] = xq[3]; fa[2] = q[2];  fa[3] = q[3];
            fb[0] = xq[6]; fb[1] = xq[7]; fb[2] = q[6];  fb[3] = q[7];
        }
        outF[2 * nt]     = fa;
        outF[2 * nt + 1] = fb;

        if (nt + 1 < NT) stage_write<KT, THREADS>(nxt, tmp, tid);
        __syncthreads();
    }
}

template<int K>
__device__ inline void layerQ(const short* __restrict__ wp,
                              const float* __restrict__ bp,
                              const u32x4* __restrict__ inF,
                              short* __restrict__ qout,
                              int lane, int h, int r0)
{
    constexpr int KT = K / 16;
    f32x16 a;
#pragma unroll
    for (int r = 0; r < 16; ++r) a[r] = 0.f;
#pragma unroll
    for (int kt = 0; kt < KT; ++kt) {
        short8 wf = *(const short8*)(wp + kt * 512 + lane * 8);
        a = __builtin_amdgcn_mfma_f32_32x32x16_bf16(
                wf, __builtin_bit_cast(short8, inF[kt]), a, 0, 0, 0);
    }
    const float* bpp = bp + h * 16;
    short* qb = qout + (size_t)(r0 + (lane & 31)) * 32 + 4 * h;
    const int fo[8] = {0, 2, 8, 10, 16, 18, 24, 26};
#pragma unroll
    for (int i = 0; i < 8; ++i) {
        float v0 = a[2 * i] + bpp[2 * i];
        float v1 = a[2 * i + 1] + bpp[2 * i + 1];
        *(unsigned*)(qb + fo[i]) = pkbf(v0, v1);
    }
}

__global__ void __launch_bounds__(512, 1) mlp_kernel(
    const float* __restrict__ hid,
    const short* __restrict__ wp,
    const float* __restrict__ biasP,
    short* __restrict__ qout)
{
    __shared__ __align__(16) short sW0[8192];
    __shared__ __align__(16) short sW1[8192];

    const int tid  = threadIdx.x;
    const int lane = tid & 63;
    const int wv   = tid >> 6;            // 0..7
    const int h = lane >> 5, b = lane & 31;
    const int r0 = blockIdx.x * 256 + wv * 32;

    u32x4 A[16], B[16], C[8], D[4], E[2];
    const float* hb = hid + (size_t)(r0 + b) * 256 + h * 8;
#pragma unroll
    for (int kt = 0; kt < 16; ++kt) {
        float4 x = *(const float4*)(hb + kt * 16);
        float4 y = *(const float4*)(hb + kt * 16 + 4);
        u32x4 f;
        f[0] = pkbf(x.x, x.y); f[1] = pkbf(x.z, x.w);
        f[2] = pkbf(y.x, y.y); f[3] = pkbf(y.z, y.w);
        A[kt] = f;
    }
    layerS<256, 256, true, 512>(wp,          biasP,       A, B, sW0, sW1, tid, lane, h);
    layerS<256, 128, true, 512>(wp + 65536,  biasP + 256, B, C, sW0, sW1, tid, lane, h);
    layerS<128,  64, true, 512>(wp + 98304,  biasP + 384, C, D, sW0, sW1, tid, lane, h);
    layerS< 64,  32, true, 512>(wp + 106496, biasP + 448, D, E, sW0, sW1, tid, lane, h);
    layerQ< 32>                (wp + 108544, biasP + 480, E, qout, lane, h, r0);
}

// ---------------------------------------------------------------------------
// Kernel 2 v13: R14 no-barrier body, TWO sequential 16-el tiles per wave
// (grid NB/128 = 512).  Cross-tile ILP at phase boundaries; resident
// waves de-phase (mixed VALU/LDS/VMEM demand).  LDS 38400 B -> 4 WG/CU.
// ---------------------------------------------------------------------------
__global__ void __launch_bounds__(256, 2) conv_attn_kernel(
    const float* __restrict__ Xg,
    const short* __restrict__ weffT,
    const float* __restrict__ beff,
    const short* __restrict__ aw0T, const float* __restrict__ ab0,
    const short* __restrict__ aw1T, const float* __restrict__ ab1,
    const float* __restrict__ sTab,
    const short* __restrict__ qb16,
    float* __restrict__ out)
{
    __shared__ __align__(16) short sPool[4][4800];

    const int tid    = threadIdx.x;
    const int w      = tid >> 6;
    const int lane   = tid & 63;
    const int lanelo = lane & 15;
    const int g      = lane >> 4;

    short* sKc = &sPool[w][0];      // [16][100]
    short* sVc = &sPool[w][1600];   // [16][200]
    short* sAh = &sPool[w][0];      // overlays Kc after S1
    short* sHh = &sPool[w][1024];

    const int elq = lane >> 2, qiq = lane & 3;

    // hoisted bias prefetch (tile-invariant)
    float bv[19];
#pragma unroll
    for (int nt = 0; nt < 19; ++nt) bv[nt] = beff[nt * 16 + lanelo];

    for (int t = 0; t < 2; ++t) {
        const int e0 = blockIdx.x * 128 + t * 64 + w * 16;

        // ---- hoisted q load ----
        short8 qv = *(const short8*)(qb16 + (size_t)(e0 + elq) * 32 + qiq * 8);

        // ---- A-fragments direct from global X ----
        short8 af[5];
        {
            const float* xr = Xg + (size_t)(e0 + lanelo) * 147;
            const int c0g = g * 8;
#pragma unroll
            for (int kt = 0; kt < 5; ++kt) {
                int c0 = kt * 32 + c0g;
                float v[8];
#pragma unroll
                for (int j = 0; j < 8; ++j) {
                    int c = c0 + j;
                    v[j] = (c < 147) ? xr[c] : 0.f;
                }
                u32x4 u;
                u[0] = pkbf(v[0], v[1]); u[1] = pkbf(v[2], v[3]);
                u[2] = pkbf(v[4], v[5]); u[3] = pkbf(v[6], v[7]);
                af[kt] = __builtin_bit_cast(short8, u);
            }
        }

        // ---- conv GEMM: 19 n-tiles x 5 k-tiles, B prefetch depth 2 ----
        short8 bf[3][5];
        {
            const short* wb0 = weffT + lanelo * 160 + g * 8;
            const short* wb1 = weffT + (16 + lanelo) * 160 + g * 8;
#pragma unroll
            for (int kt = 0; kt < 5; ++kt) {
                bf[0][kt] = *(const short8*)(wb0 + kt * 32);
                bf[1][kt] = *(const short8*)(wb1 + kt * 32);
            }
        }
#pragma unroll
        for (int nt = 0; nt < 19; ++nt) {
            if (nt + 2 < 19) {
                const short* wb = weffT + ((nt + 2) * 16 + lanelo) * 160 + g * 8;
#pragma unroll
                for (int kt = 0; kt < 5; ++kt)
                    bf[(nt + 2) % 3][kt] = *(const short8*)(wb + kt * 32);
            }
            f32x4 a; a[0] = 0.f; a[1] = 0.f; a[2] = 0.f; a[3] = 0.f;
#pragma unroll
            for (int kt = 0; kt < 5; ++kt)
                a = __builtin_amdgcn_mfma_f32_16x16x32_bf16(af[kt], bf[nt % 3][kt], a, 0, 0, 0);
            int n = nt * 16 + lanelo;
            if (n < 300) {
                int p = n / 12, c = n - p * 12;
#pragma unroll
                for (int j = 0; j < 4; ++j) {
                    int el = g * 4 + j;
                    float v = a[j] + bv[nt];
                    if (c < 4) sKc[el * 100 + p * 4 + c]       = f2bf(v);
                    else       sVc[el * 200 + p * 8 + (c - 4)] = f2bf(v);
                }
            }
        }

        // ---- S1: attention, lane = (el, qi); 5-position chunks ----
        {
            const int el = elq, qi = qiq;
            float qf[8];
#pragma unroll
            for (int i = 0; i < 8; ++i) qf[i] = b2f(qv[i]);

            float lg[25];
            float mx = -1e30f;
#pragma unroll
            for (int c = 0; c < 5; ++c) {
                short4v kv[5]; float4 sv[5];
#pragma unroll
                for (int i = 0; i < 5; ++i) {
                    int p = c * 5 + i;
                    kv[i] = *(const short4v*)(sKc + el * 100 + p * 4);
                    sv[i] = *(const float4*)(sTab + p * 4);
                }
#pragma unroll
                for (int i = 0; i < 5; ++i) {
                    float s = b2f(kv[i][0]) * qf[0] + b2f(kv[i][1]) * qf[1]
                            + b2f(kv[i][2]) * qf[2] + b2f(kv[i][3]) * qf[3]
                            + sv[i].x * qf[4] + sv[i].y * qf[5]
                            + sv[i].z * qf[6] + sv[i].w * qf[7];
                    lg[c * 5 + i] = s;
                    mx = fmaxf(mx, s);
                }
            }
            float sum = 0.f;
#pragma unroll
            for (int p = 0; p < 25; ++p) { lg[p] = __expf(lg[p] - mx); sum += lg[p]; }
            float inv = 1.f / sum;

            float o[12];
#pragma unroll
            for (int d = 0; d < 12; ++d) o[d] = 0.f;
#pragma unroll
            for (int c = 0; c < 5; ++c) {
                short4v v0[5], v1[5]; float4 sv[5];
#pragma unroll
                for (int i = 0; i < 5; ++i) {
                    int p = c * 5 + i;
                    v0[i] = *(const short4v*)(sVc + el * 200 + p * 8);
                    v1[i] = *(const short4v*)(sVc + el * 200 + p * 8 + 4);
                    sv[i] = *(const float4*)(sTab + p * 4);
                }
#pragma unroll
                for (int i = 0; i < 5; ++i) {
                    float wgt = lg[c * 5 + i];
                    o[0] += wgt * b2f(v0[i][0]); o[1] += wgt * b2f(v0[i][1]);
                    o[2] += wgt * b2f(v0[i][2]); o[3] += wgt * b2f(v0[i][3]);
                    o[4] += wgt * b2f(v1[i][0]); o[5] += wgt * b2f(v1[i][1]);
                    o[6] += wgt * b2f(v1[i][2]); o[7] += wgt * b2f(v1[i][3]);
                    o[8]  += wgt * sv[i].x; o[9]  += wgt * sv[i].y;
                    o[10] += wgt * sv[i].z; o[11] += wgt * sv[i].w;
                }
            }
#pragma unroll
            for (int d = 0; d < 12; ++d) {
                int col = qi * 12 + d;
                int ch = col >> 3;
                sAh[el * 64 + ((ch ^ (el & 7)) << 3) + (col & 7)] = f2bf(o[d] * inv);
            }
#pragma unroll
            for (int z = 0; z < 4; ++z) {
                int col = 48 + qi * 4 + z;
                int ch = col >> 3;
                sAh[el * 64 + ((ch ^ (el & 7)) << 3) + (col & 7)] = 0;
            }
        }

        // ---- S2: h1 = relu(a @ aw0 + ab0), MFMA M16 K64 N32 ----
        {
            short8 bw0a = *(const short8*)(aw0T + (0 * 16 + lanelo) * 64 + g * 8);
            short8 bw1a = *(const short8*)(aw0T + (0 * 16 + lanelo) * 64 + 32 + g * 8);
            short8 bw0b = *(const short8*)(aw0T + (1 * 16 + lanelo) * 64 + g * 8);
            short8 bw1b = *(const short8*)(aw0T + (1 * 16 + lanelo) * 64 + 32 + g * 8);
            float bba = ab0[lanelo];
            float bbb = ab0[16 + lanelo];

            short8 aa0, aa1;
            {
                int p0 = (0 * 4 + g) ^ (lanelo & 7);
                int p1 = (1 * 4 + g) ^ (lanelo & 7);
                aa0 = *(const short8*)(sAh + lanelo * 64 + p0 * 8);
                aa1 = *(const short8*)(sAh + lanelo * 64 + p1 * 8);
            }
            f32x4 h0; h0[0] = 0.f; h0[1] = 0.f; h0[2] = 0.f; h0[3] = 0.f;
            f32x4 h1 = h0;
            h0 = __builtin_amdgcn_mfma_f32_16x16x32_bf16(aa0, bw0a, h0, 0, 0, 0);
            h0 = __builtin_amdgcn_mfma_f32_16x16x32_bf16(aa1, bw1a, h0, 0, 0, 0);
            h1 = __builtin_amdgcn_mfma_f32_16x16x32_bf16(aa0, bw0b, h1, 0, 0, 0);
            h1 = __builtin_amdgcn_mfma_f32_16x16x32_bf16(aa1, bw1b, h1, 0, 0, 0);
#pragma unroll
            for (int j = 0; j < 4; ++j) {
                int row = g * 4 + j;
                int n0 = lanelo, n1 = 16 + lanelo;
                float va = fmaxf(h0[j] + bba, 0.f);
                float vb = fmaxf(h1[j] + bbb, 0.f);
                sHh[row * 32 + (((n0 >> 3) ^ (row & 3)) << 3) + (n0 & 7)] = f2bf(va);
                sHh[row * 32 + (((n1 >> 3) ^ (row & 3)) << 3) + (n1 & 7)] = f2bf(vb);
            }
        }

        // ---- S3: out = h1 @ aw1 + ab1, MFMA M16 K32 N64 ----
        {
            short8 bw[4]; float bb[4];
#pragma unroll
            for (int nt3 = 0; nt3 < 4; ++nt3) {
                int n = nt3 * 16 + lanelo;
                bw[nt3] = *(const short8*)(aw1T + n * 32 + g * 8);
                bb[nt3] = ab1[n];
            }
            short8 ah;
            {
                int ph = (g ^ (lanelo & 3));
                ah = *(const short8*)(sHh + lanelo * 32 + ph * 8);
            }
#pragma unroll
            for (int nt3 = 0; nt3 < 4; ++nt3) {
                int n = nt3 * 16 + lanelo;
                f32x4 oacc; oacc[0] = 0.f; oacc[1] = 0.f; oacc[2] = 0.f; oacc[3] = 0.f;
                oacc = __builtin_amdgcn_mfma_f32_16x16x32_bf16(ah, bw[nt3], oacc, 0, 0, 0);
#pragma unroll
                for (int j = 0; j < 4; ++j) {
                    int el = g * 4 + j;
                    out[((size_t)e0 + el) * 64 + n] = oacc[j] + bb[nt3];
                }
            }
        }
    }   // tile loop
}

// ---------------------------------------------------------------------------

extern "C" void kernel_launch(void* const* d_in, const int* in_sizes, int n_in,
                              void* d_out, int out_size, void* d_ws, size_t ws_size,
                              hipStream_t stream)
{
    const float* X   = (const float*)d_in[0];
    const float* hid = (const float*)d_in[1];
    const float* c1w = (const float*)d_in[2];
    const float* c1b = (const float*)d_in[3];
    const float* c2w = (const float*)d_in[4];
    const float* c2b = (const float*)d_in[5];
    const float* qw0 = (const float*)d_in[6];
    const float* qb0 = (const float*)d_in[7];
    const float* qw1 = (const float*)d_in[8];
    const float* qb1 = (const float*)d_in[9];
    const float* qw2 = (const float*)d_in[10];
    const float* qb2 = (const float*)d_in[11];
    const float* qw3 = (const float*)d_in[12];
    const float* qb3 = (const float*)d_in[13];
    const float* qw4 = (const float*)d_in[14];
    const float* qb4 = (const float*)d_in[15];
    const float* aw0 = (const float*)d_in[16];
    const float* ab0 = (const float*)d_in[17];
    const float* aw1 = (const float*)d_in[18];
    const float* ab1 = (const float*)d_in[19];

    float* out   = (float*)d_out;
    short* qb16  = (short*)d_ws;
    short* wsW   = qb16 + (size_t)NB * 32;
    short* weffT = wsW + MLPW_CNT;
    float* beff  = (float*)(weffT + WEFF_CNT);
    short* aw0T  = (short*)(beff + 320);
    short* aw1T  = aw0T + 2048;
    float* sTab  = (float*)(aw1T + 2048);
    float* biasP = sTab + 100;

    hipLaunchKernelGGL(prep_kernel, dim3((PREP_TOT + 255) / 256), dim3(256), 0, stream,
                       qw0, qw1, qw2, qw3, qw4, qb0, qb1, qb2, qb3, qb4,
                       c1w, c1b, c2w, c2b, aw0, aw1,
                       wsW, weffT, beff, aw0T, aw1T, sTab, biasP);
    hipLaunchKernelGGL(mlp_kernel, dim3(NB / 256), dim3(512), 0, stream,
                       hid, wsW, biasP, qb16);
    hipLaunchKernelGGL(conv_attn_kernel, dim3(NB / 128), dim3(256), 0, stream,
                       X, weffT, beff, aw0T, ab0, aw1T, ab1, sTab, qb16, out);
}

// Round 21
// 71.767 us; speedup vs baseline: 2.4219x; 2.4219x over previous
//
#include <hip/hip_runtime.h>
#include <hip/hip_bf16.h>

#define NB 65536

typedef __attribute__((ext_vector_type(8))) short short8;
typedef __attribute__((ext_vector_type(4))) short short4v;
typedef __attribute__((ext_vector_type(4))) float f32x4;
typedef __attribute__((ext_vector_type(16))) float f32x16;
typedef __attribute__((ext_vector_type(4))) unsigned int u32x4;

__device__ inline short f2bf(float f) {
    unsigned u = __builtin_bit_cast(unsigned, f);
    unsigned r = (u + 0x7fffu + ((u >> 16) & 1u)) >> 16;   // RNE
    return (short)(unsigned short)r;
}
__device__ inline float b2f(short s) {
    return __builtin_bit_cast(float, (unsigned)((unsigned short)s) << 16);
}
__device__ inline unsigned pkbf(float lo, float hi) {
    return ((unsigned)(unsigned short)f2bf(hi) << 16) | (unsigned)(unsigned short)f2bf(lo);
}

#define MLPW_CNT 109568
#define WEFF_CNT 51200
// prep index-space extents
#define A0 (MLPW_CNT + WEFF_CNT + 320)   // aw0T start
#define A1 (A0 + 2048)                   // aw1T start
#define A2 (A1 + 2048)                   // sTab start
#define A3 (A2 + 100)                    // biasP start (512 f32)
#define PREP_TOT (A3 + 512)

// ---------------------------------------------------------------------------
// Kernel 0: prep (proven)
// ---------------------------------------------------------------------------
__global__ void __launch_bounds__(256) prep_kernel(
    const float* __restrict__ w0, const float* __restrict__ w1,
    const float* __restrict__ w2, const float* __restrict__ w3,
    const float* __restrict__ w4,
    const float* __restrict__ b0, const float* __restrict__ b1,
    const float* __restrict__ b2, const float* __restrict__ b3,
    const float* __restrict__ b4,
    const float* __restrict__ c1w, const float* __restrict__ c1b,
    const float* __restrict__ c2w, const float* __restrict__ c2b,
    const float* __restrict__ aw0, const float* __restrict__ aw1,
    short* __restrict__ wt, short* __restrict__ weff, float* __restrict__ beff,
    short* __restrict__ aw0T, short* __restrict__ aw1T, float* __restrict__ sTab,
    float* __restrict__ biasP)
{
    int idx = blockIdx.x * 256 + threadIdx.x;
    if (idx < MLPW_CNT) {
        const float* W; int N, KT, base;
        if (idx < 65536)       { W = w0; N = 256; KT = 16; base = 0; }
        else if (idx < 98304)  { W = w1; N = 128; KT = 16; base = 65536; }
        else if (idx < 106496) { W = w2; N = 64;  KT = 8;  base = 98304; }
        else if (idx < 108544) { W = w3; N = 32;  KT = 4;  base = 106496; }
        else                   { W = w4; N = 32;  KT = 2;  base = 108544; }
        int i  = idx - base;
        int nt = i / (KT * 512);
        int r1 = i - nt * (KT * 512);
        int kt = r1 >> 9;
        int l  = (r1 & 511) >> 3;
        int j  = i & 7;
        int n  = nt * 32 + (l & 31);
        int k  = kt * 16 + ((l >> 5) << 3) + j;
        wt[idx] = f2bf(W[k * N + n]);
    } else if (idx < MLPW_CNT + WEFF_CNT) {
        int it = idx - MLPW_CNT;
        int n = it / 160, k = it - n * 160;
        float acc = 0.f;
        if (n < 300 && k < 147) {
            int oc = n % 12, p = n / 12, oy = p / 5, ox = p - oy * 5;
            int ci = k % 3,  t = k / 3, iy = t / 7, ix = t - iy * 7;
            for (int y = 0; y < 5; ++y) {
                int ky = iy - y + 1, ly = y - oy + 1;
                if ((unsigned)ky < 5u && (unsigned)ly < 3u) {
                    for (int x = 0; x < 5; ++x) {
                        int kx = ix - x + 1, lx = x - ox + 1;
                        if ((unsigned)kx < 5u && (unsigned)lx < 3u) {
                            const float* p1 = c1w + ((ky * 5 + kx) * 3 + ci) * 8;
                            const float* p2 = c2w + ((ly * 3 + lx) * 8) * 12 + oc;
#pragma unroll
                            for (int c = 0; c < 8; ++c) acc += p1[c] * p2[c * 12];
                        }
                    }
                }
            }
        }
        weff[it] = f2bf(acc);
    } else if (idx < A0) {
        int n = idx - MLPW_CNT - WEFF_CNT;
        float acc = 0.f;
        if (n < 300) {
            int oc = n % 12, p = n / 12, oy = p / 5, ox = p - oy * 5;
            acc = c2b[oc];
            for (int y = 0; y < 5; ++y) {
                int ly = y - oy + 1;
                if ((unsigned)ly < 3u) {
                    for (int x = 0; x < 5; ++x) {
                        int lx = x - ox + 1;
                        if ((unsigned)lx < 3u) {
#pragma unroll
                            for (int c = 0; c < 8; ++c)
                                acc += c2w[((ly * 3 + lx) * 8 + c) * 12 + oc] * c1b[c];
                        }
                    }
                }
            }
        }
        beff[n] = acc;
    } else if (idx < A1) {
        int t = idx - A0;
        int n = t >> 6, k = t & 63;           // [32][64]
        aw0T[t] = (k < 48) ? f2bf(aw0[k * 32 + n]) : (short)0;
    } else if (idx < A2) {
        int t = idx - A1;
        int n = t >> 5, k = t & 31;           // [64][32]
        aw1T[t] = f2bf(aw1[k * 64 + n]);
    } else if (idx < A3) {
        int i = idx - A2;
        int p = i >> 2, s = i & 3;
        int h = p / 5, w = p - 5 * h;
        int u = (s >> 1) + 1, v = (s & 1) + 1;
        const float PI5 = 0.6283185307179586f;
        sTab[i] = cosf(((float)(h + 1) * PI5) * (float)u) *
                  cosf(((float)(w + 1) * PI5) * (float)v);
    } else if (idx < PREP_TOT) {
        int t = idx - A3;
        const float* B; int N, base;
        if (t < 256)      { B = b0; N = 256; base = 0; }
        else if (t < 384) { B = b1; N = 128; base = 256; }
        else if (t < 448) { B = b2; N = 64;  base = 384; }
        else if (t < 480) { B = b3; N = 32;  base = 448; }
        else              { B = b4; N = 32;  base = 480; }
        int u  = t - base;
        int h  = u / (N / 2);
        int w  = u - h * (N / 2);
        int nt = w >> 4, r = w & 15;
        biasP[t] = B[nt * 32 + (r & 3) + 8 * (r >> 2) + 4 * h];
    }
}

// ---------------------------------------------------------------------------
// Kernel 1 v5: register-resident MLP, LDS-staged weights, 8 waves/WG.
// ---------------------------------------------------------------------------
template<int KT, int THREADS>
__device__ inline void stage_load(const short* __restrict__ src,
                                  short8* r, int tid)
{
    constexpr int CNT = (KT * 64 + THREADS - 1) / THREADS;
#pragma unroll
    for (int i = 0; i < CNT; ++i) {
        int idx = tid + i * THREADS;
        if (idx < KT * 64) r[i] = *(const short8*)(src + idx * 8);
    }
}
template<int KT, int THREADS>
__device__ inline void stage_write(short* __restrict__ dst,
                                   const short8* r, int tid)
{
    constexpr int CNT = (KT * 64 + THREADS - 1) / THREADS;
#pragma unroll
    for (int i = 0; i < CNT; ++i) {
        int idx = tid + i * THREADS;
        if (idx < KT * 64) *(short8*)(dst + idx * 8) = r[i];
    }
}

template<int K, int N, bool RELU, int THREADS>
__device__ inline void layerS(const short* __restrict__ wp,
                              const float* __restrict__ bp,
                              const u32x4* __restrict__ inF,
                              u32x4* __restrict__ outF,
                              short* __restrict__ sW0,
                              short* __restrict__ sW1,
                              int tid, int lane, int h)
{
    constexpr int KT = K / 16, NT = N / 32;
    constexpr int CNT = (KT * 64 + THREADS - 1) / THREADS;
    short8 tmp[CNT];

    stage_load<KT, THREADS>(wp, tmp, tid);
    stage_write<KT, THREADS>(sW0, tmp, tid);
    __syncthreads();

#pragma unroll
    for (int nt = 0; nt < NT; ++nt) {
        short* cur = (nt & 1) ? sW1 : sW0;
        short* nxt = (nt & 1) ? sW0 : sW1;
        if (nt + 1 < NT) stage_load<KT, THREADS>(wp + (nt + 1) * KT * 512, tmp, tid);

        f32x16 a;
#pragma unroll
        for (int r = 0; r < 16; ++r) a[r] = 0.f;
#pragma unroll
        for (int kt = 0; kt < KT; ++kt) {
            short8 wf = *(const short8*)(cur + kt * 512 + lane * 8);
            a = __builtin_amdgcn_mfma_f32_32x32x16_bf16(
                    wf, __builtin_bit_cast(short8, inF[kt]), a, 0, 0, 0);
        }
        const float* bpp = bp + h * (N / 2) + nt * 16;
        unsigned q[8];
#pragma unroll
        for (int i = 0; i < 8; ++i) {
            float v0 = a[2 * i] + bpp[2 * i];
            float v1 = a[2 * i + 1] + bpp[2 * i + 1];
            if (RELU) { v0 = fmaxf(v0, 0.f); v1 = fmaxf(v1, 0.f); }
            q[i] = pkbf(v0, v1);
        }
        unsigned xq[8];
#pragma unroll
        for (int i = 0; i < 8; ++i) xq[i] = (unsigned)__shfl_xor((int)q[i], 32, 64);
        u32x4 fa, fb;
        if (h == 0) {
            fa[0] = q[0];  fa[1] = q[1];  fa[2] = xq[0]; fa[3] = xq[1];
            fb[0] = q[4];  fb[1] = q[5];  fb[2] = xq[4]; fb[3] = xq[5];
        } else {
            fa[0] = xq[2]; fa[1] = xq[3]; fa[2] = q[2];  fa[3] = q[3];
            fb[0] = xq[6]; fb[1] = xq[7]; fb[2] = q[6];  fb[3] = q[7];
        }
        outF[2 * nt]     = fa;
        outF[2 * nt + 1] = fb;

        if (nt + 1 < NT) stage_write<KT, THREADS>(nxt, tmp, tid);
        __syncthreads();
    }
}

template<int K>
__device__ inline void layerQ(const short* __restrict__ wp,
                              const float* __restrict__ bp,
                              const u32x4* __restrict__ inF,
                              short* __restrict__ qout,
                              int lane, int h, int r0)
{
    constexpr int KT = K / 16;
    f32x16 a;
#pragma unroll
    for (int r = 0; r < 16; ++r) a[r] = 0.f;
#pragma unroll
    for (int kt = 0; kt < KT; ++kt) {
        short8 wf = *(const short8*)(wp + kt * 512 + lane * 8);
        a = __builtin_amdgcn_mfma_f32_32x32x16_bf16(
                wf, __builtin_bit_cast(short8, inF[kt]), a, 0, 0, 0);
    }
    const float* bpp = bp + h * 16;
    short* qb = qout + (size_t)(r0 + (lane & 31)) * 32 + 4 * h;
    const int fo[8] = {0, 2, 8, 10, 16, 18, 24, 26};
#pragma unroll
    for (int i = 0; i < 8; ++i) {
        float v0 = a[2 * i] + bpp[2 * i];
        float v1 = a[2 * i + 1] + bpp[2 * i + 1];
        *(unsigned*)(qb + fo[i]) = pkbf(v0, v1);
    }
}

__global__ void __launch_bounds__(512, 1) mlp_kernel(
    const float* __restrict__ hid,
    const short* __restrict__ wp,
    const float* __restrict__ biasP,
    short* __restrict__ qout)
{
    __shared__ __align__(16) short sW0[8192];
    __shared__ __align__(16) short sW1[8192];

    const int tid  = threadIdx.x;
    const int lane = tid & 63;
    const int wv   = tid >> 6;            // 0..7
    const int h = lane >> 5, b = lane & 31;
    const int r0 = blockIdx.x * 256 + wv * 32;

    u32x4 A[16], B[16], C[8], D[4], E[2];
    const float* hb = hid + (size_t)(r0 + b) * 256 + h * 8;
#pragma unroll
    for (int kt = 0; kt < 16; ++kt) {
        float4 x = *(const float4*)(hb + kt * 16);
        float4 y = *(const float4*)(hb + kt * 16 + 4);
        u32x4 f;
        f[0] = pkbf(x.x, x.y); f[1] = pkbf(x.z, x.w);
        f[2] = pkbf(y.x, y.y); f[3] = pkbf(y.z, y.w);
        A[kt] = f;
    }
    layerS<256, 256, true, 512>(wp,          biasP,       A, B, sW0, sW1, tid, lane, h);
    layerS<256, 128, true, 512>(wp + 65536,  biasP + 256, B, C, sW0, sW1, tid, lane, h);
    layerS<128,  64, true, 512>(wp + 98304,  biasP + 384, C, D, sW0, sW1, tid, lane, h);
    layerS< 64,  32, true, 512>(wp + 106496, biasP + 448, D, E, sW0, sW1, tid, lane, h);
    layerQ< 32>                (wp + 108544, biasP + 480, E, qout, lane, h, r0);
}

// ---------------------------------------------------------------------------
// Kernel 2 v12 (best measured): 4 waves x 16 els, WG-shared B via
// global_load_lds double-buffer, sA/sH overlay.  grid NB/64.
// ---------------------------------------------------------------------------
typedef __attribute__((address_space(1))) const void glb_v;
typedef __attribute__((address_space(3))) void lds_v;

__global__ void __launch_bounds__(256, 3) conv_attn_kernel(
    const float* __restrict__ Xg,
    const short* __restrict__ weffT,
    const float* __restrict__ beff,
    const short* __restrict__ aw0T, const float* __restrict__ ab0,
    const short* __restrict__ aw1T, const float* __restrict__ ab1,
    const float* __restrict__ sTab,
    const short* __restrict__ qb16,
    float* __restrict__ out)
{
    __shared__ __align__(16) short sPool[4][4800];
    __shared__ __align__(16) short sB[2][2560];   // [buf][kt*512 + lane*8]

    const int tid    = threadIdx.x;
    const int w      = tid >> 6;
    const int lane   = tid & 63;
    const int lanelo = lane & 15;
    const int g      = lane >> 4;
    const int e0     = blockIdx.x * 64 + w * 16;

    short* sKc = &sPool[w][0];      // [16][100]
    short* sVc = &sPool[w][1600];   // [16][200]
    short* sAh = &sPool[w][0];      // overlays Kc after S1
    short* sHh = &sPool[w][1024];

    const int elq = lane >> 2, qiq = lane & 3;
    short8 qv = *(const short8*)(qb16 + (size_t)(e0 + elq) * 32 + qiq * 8);

    // ---- A-fragments DIRECT from global X ----
    short8 af[5];
    {
        const float* xr = Xg + (size_t)(e0 + lanelo) * 147;
        const int c0g = g * 8;
#pragma unroll
        for (int kt = 0; kt < 5; ++kt) {
            int c0 = kt * 32 + c0g;
            float v[8];
#pragma unroll
            for (int j = 0; j < 8; ++j) {
                int c = c0 + j;
                v[j] = (c < 147) ? xr[c] : 0.f;
            }
            u32x4 u;
            u[0] = pkbf(v[0], v[1]); u[1] = pkbf(v[2], v[3]);
            u[2] = pkbf(v[4], v[5]); u[3] = pkbf(v[6], v[7]);
            af[kt] = __builtin_bit_cast(short8, u);
        }
    }

    float bv[19];
#pragma unroll
    for (int nt = 0; nt < 19; ++nt) bv[nt] = beff[nt * 16 + lanelo];

#define STAGE_B(NT_, BUF_)                                                     \
    {                                                                          \
        const short* src0 = weffT + ((NT_) * 16 + lanelo) * 160 + w * 32 + g * 8; \
        __builtin_amdgcn_global_load_lds((glb_v*)src0,                         \
            (lds_v*)(&sB[BUF_][w * 512]), 16, 0, 0);                           \
        if (w == 0) {                                                          \
            const short* src1 = weffT + ((NT_) * 16 + lanelo) * 160 + 4 * 32 + g * 8; \
            __builtin_amdgcn_global_load_lds((glb_v*)src1,                     \
                (lds_v*)(&sB[BUF_][4 * 512]), 16, 0, 0);                       \
        }                                                                      \
    }

    STAGE_B(0, 0)
    __syncthreads();

#pragma unroll
    for (int nt = 0; nt < 19; ++nt) {
        const int cur = nt & 1;
        if (nt + 1 < 19) {
            if ((nt & 1) == 0) { STAGE_B(nt + 1, 1) }
            else               { STAGE_B(nt + 1, 0) }
        }
        f32x4 a; a[0] = 0.f; a[1] = 0.f; a[2] = 0.f; a[3] = 0.f;
#pragma unroll
        for (int kt = 0; kt < 5; ++kt) {
            short8 bfv = *(const short8*)(&sB[cur][kt * 512 + lane * 8]);
            a = __builtin_amdgcn_mfma_f32_16x16x32_bf16(af[kt], bfv, a, 0, 0, 0);
        }
        int n = nt * 16 + lanelo;
        if (n < 300) {
            int p = n / 12, c = n - p * 12;
#pragma unroll
            for (int j = 0; j < 4; ++j) {
                int el = g * 4 + j;
                float v = a[j] + bv[nt];
                if (c < 4) sKc[el * 100 + p * 4 + c]       = f2bf(v);
                else       sVc[el * 200 + p * 8 + (c - 4)] = f2bf(v);
            }
        }
        __syncthreads();
    }
#undef STAGE_B

    // ---- S1: attention ----
    {
        const int el = elq, qi = qiq;
        float qf[8];
#pragma unroll
        for (int i = 0; i < 8; ++i) qf[i] = b2f(qv[i]);

        float lg[25];
        float mx = -1e30f;
#pragma unroll
        for (int c = 0; c < 5; ++c) {
            short4v kv[5]; float4 sv[5];
#pragma unroll
            for (int i = 0; i < 5; ++i) {
                int p = c * 5 + i;
                kv[i] = *(const short4v*)(sKc + el * 100 + p * 4);
                sv[i] = *(const float4*)(sTab + p * 4);
            }
#pragma unroll
            for (int i = 0; i < 5; ++i) {
                float s = b2f(kv[i][0]) * qf[0] + b2f(kv[i][1]) * qf[1]
                        + b2f(kv[i][2]) * qf[2] + b2f(kv[i][3]) * qf[3]
                        + sv[i].x * qf[4] + sv[i].y * qf[5]
                        + sv[i].z * qf[6] + sv[i].w * qf[7];
                lg[c * 5 + i] = s;
                mx = fmaxf(mx, s);
            }
        }
        float sum = 0.f;
#pragma unroll
        for (int p = 0; p < 25; ++p) { lg[p] = __expf(lg[p] - mx); sum += lg[p]; }
        float inv = 1.f / sum;

        float o[12];
#pragma unroll
        for (int d = 0; d < 12; ++d) o[d] = 0.f;
#pragma unroll
        for (int c = 0; c < 5; ++c) {
            short4v v0[5], v1[5]; float4 sv[5];
#pragma unroll
            for (int i = 0; i < 5; ++i) {
                int p = c * 5 + i;
                v0[i] = *(const short4v*)(sVc + el * 200 + p * 8);
                v1[i] = *(const short4v*)(sVc + el * 200 + p * 8 + 4);
                sv[i] = *(const float4*)(sTab + p * 4);
            }
#pragma unroll
            for (int i = 0; i < 5; ++i) {
                float wgt = lg[c * 5 + i];
                o[0] += wgt * b2f(v0[i][0]); o[1] += wgt * b2f(v0[i][1]);
                o[2] += wgt * b2f(v0[i][2]); o[3] += wgt * b2f(v0[i][3]);
                o[4] += wgt * b2f(v1[i][0]); o[5] += wgt * b2f(v1[i][1]);
                o[6] += wgt * b2f(v1[i][2]); o[7] += wgt * b2f(v1[i][3]);
                o[8]  += wgt * sv[i].x; o[9]  += wgt * sv[i].y;
                o[10] += wgt * sv[i].z; o[11] += wgt * sv[i].w;
            }
        }
#pragma unroll
        for (int d = 0; d < 12; ++d) {
            int col = qi * 12 + d;
            int ch = col >> 3;
            sAh[el * 64 + ((ch ^ (el & 7)) << 3) + (col & 7)] = f2bf(o[d] * inv);
        }
#pragma unroll
        for (int z = 0; z < 4; ++z) {
            int col = 48 + qi * 4 + z;
            int ch = col >> 3;
            sAh[el * 64 + ((ch ^ (el & 7)) << 3) + (col & 7)] = 0;
        }
    }

    // ---- S2 ----
    {
        short8 bw0a = *(const short8*)(aw0T + (0 * 16 + lanelo) * 64 + g * 8);
        short8 bw1a = *(const short8*)(aw0T + (0 * 16 + lanelo) * 64 + 32 + g * 8);
        short8 bw0b = *(const short8*)(aw0T + (1 * 16 + lanelo) * 64 + g * 8);
        short8 bw1b = *(const short8*)(aw0T + (1 * 16 + lanelo) * 64 + 32 + g * 8);
        float bba = ab0[lanelo];
        float bbb = ab0[16 + lanelo];

        short8 aa0, aa1;
        {
            int p0 = (0 * 4 + g) ^ (lanelo & 7);
            int p1 = (1 * 4 + g) ^ (lanelo & 7);
            aa0 = *(const short8*)(sAh + lanelo * 64 + p0 * 8);
            aa1 = *(const short8*)(sAh + lanelo * 64 + p1 * 8);
        }
        f32x4 h0; h0[0] = 0.f; h0[1] = 0.f; h0[2] = 0.f; h0[3] = 0.f;
        f32x4 h1 = h0;
        h0 = __builtin_amdgcn_mfma_f32_16x16x32_bf16(aa0, bw0a, h0, 0, 0, 0);
        h0 = __builtin_amdgcn_mfma_f32_16x16x32_bf16(aa1, bw1a, h0, 0, 0, 0);
        h1 = __builtin_amdgcn_mfma_f32_16x16x32_bf16(aa0, bw0b, h1, 0, 0, 0);
        h1 = __builtin_amdgcn_mfma_f32_16x16x32_bf16(aa1, bw1b, h1, 0, 0, 0);
#pragma unroll
        for (int j = 0; j < 4; ++j) {
            int row = g * 4 + j;
            int n0 = lanelo, n1 = 16 + lanelo;
            float va = fmaxf(h0[j] + bba, 0.f);
            float vb = fmaxf(h1[j] + bbb, 0.f);
            sHh[row * 32 + (((n0 >> 3) ^ (row & 3)) << 3) + (n0 & 7)] = f2bf(va);
            sHh[row * 32 + (((n1 >> 3) ^ (row & 3)) << 3) + (n1 & 7)] = f2bf(vb);
        }
    }

    // ---- S3 ----
    {
        short8 bw[4]; float bb[4];
#pragma unroll
        for (int nt3 = 0; nt3 < 4; ++nt3) {
            int n = nt3 * 16 + lanelo;
            bw[nt3] = *(const short8*)(aw1T + n * 32 + g * 8);
            bb[nt3] = ab1[n];
        }
        short8 ah;
        {
            int ph = (g ^ (lanelo & 3));
            ah = *(const short8*)(sHh + lanelo * 32 + ph * 8);
        }
#pragma unroll
        for (int nt3 = 0; nt3 < 4; ++nt3) {
            int n = nt3 * 16 + lanelo;
            f32x4 oacc; oacc[0] = 0.f; oacc[1] = 0.f; oacc[2] = 0.f; oacc[3] = 0.f;
            oacc = __builtin_amdgcn_mfma_f32_16x16x32_bf16(ah, bw[nt3], oacc, 0, 0, 0);
#pragma unroll
            for (int j = 0; j < 4; ++j) {
                int el = g * 4 + j;
                out[((size_t)e0 + el) * 64 + n] = oacc[j] + bb[nt3];
            }
        }
    }
}

// ---------------------------------------------------------------------------

extern "C" void kernel_launch(void* const* d_in, const int* in_sizes, int n_in,
                              void* d_out, int out_size, void* d_ws, size_t ws_size,
                              hipStream_t stream)
{
    const float* X   = (const float*)d_in[0];
    const float* hid = (const float*)d_in[1];
    const float* c1w = (const float*)d_in[2];
    const float* c1b = (const float*)d_in[3];
    const float* c2w = (const float*)d_in[4];
    const float* c2b = (const float*)d_in[5];
    const float* qw0 = (const float*)d_in[6];
    const float* qb0 = (const float*)d_in[7];
    const float* qw1 = (const float*)d_in[8];
    const float* qb1 = (const float*)d_in[9];
    const float* qw2 = (const float*)d_in[10];
    const float* qb2 = (const float*)d_in[11];
    const float* qw3 = (const float*)d_in[12];
    const float* qb3 = (const float*)d_in[13];
    const float* qw4 = (const float*)d_in[14];
    const float* qb4 = (const float*)d_in[15];
    const float* aw0 = (const float*)d_in[16];
    const float* ab0 = (const float*)d_in[17];
    const float* aw1 = (const float*)d_in[18];
    const float* ab1 = (const float*)d_in[19];

    float* out   = (float*)d_out;
    short* qb16  = (short*)d_ws;
    short* wsW   = qb16 + (size_t)NB * 32;
    short* weffT = wsW + MLPW_CNT;
    float* beff  = (float*)(weffT + WEFF_CNT);
    short* aw0T  = (short*)(beff + 320);
    short* aw1T  = aw0T + 2048;
    float* sTab  = (float*)(aw1T + 2048);
    float* biasP = sTab + 100;

    hipLaunchKernelGGL(prep_kernel, dim3((PREP_TOT + 255) / 256), dim3(256), 0, stream,
                       qw0, qw1, qw2, qw3, qw4, qb0, qb1, qb2, qb3, qb4,
                       c1w, c1b, c2w, c2b, aw0, aw1,
                       wsW, weffT, beff, aw0T, aw1T, sTab, biasP);
    hipLaunchKernelGGL(mlp_kernel, dim3(NB / 256), dim3(512), 0, stream,
                       hid, wsW, biasP, qb16);
    hipLaunchKernelGGL(conv_attn_kernel, dim3(NB / 64), dim3(256), 0, stream,
                       X, weffT, beff, aw0T, ab0, aw1T, ab1, sTab, qb16, out);
}